// Round 9
// baseline (21124.280 us; speedup 1.0000x reference)
//
#include <hip/hip_runtime.h>
#include <math.h>

// ---------------- problem constants ----------------
#define BSZ   64
#define NXDIM 729
#define NXP   736          // padded (multiple of 16), pad cols are zero
#define MDIM  324
#define MP    328          // padded vector length for m-dim arrays
#define LDA   328          // ADAT leading dim (floats)
#define EPSF  0.1f
#define SIGF  0.1f
#define NIT   30

// Cholesky blocking
#define NB    36
#define NPAN  9            // 324 / 36
#define CTHR  1024
#define PSTR  356          // P panel stride: tiles overshoot cols to at most 355

// ADAT tiling: 64x64 tiles over 6x6 upper -> 21 pairs, vector f32 FMA
#define AKC   16
#define ANCH  46           // 736 / 16

typedef unsigned long long ull;

// ---------------- setup kernels ----------------

__global__ void k_setupA(const float* __restrict__ Af,
                         float* __restrict__ A32, float* __restrict__ AT32) {
  int idx = blockIdx.x * 256 + threadIdx.x;
  if (idx < MDIM * NXP) {
    int r = idx / NXP, c = idx % NXP;
    A32[idx] = (c < NXDIM) ? Af[r * NXDIM + c] : 0.0f;
  }
  if (idx < NXP * MP) {
    int i = idx / MP, m = idx % MP;
    AT32[idx] = (i < NXDIM && m < MDIM) ? Af[m * NXDIM + i] : 0.0f;
  }
}

__global__ void k_setupState(const float* __restrict__ puz,
                             float* __restrict__ p, float* __restrict__ z,
                             float* __restrict__ lam, float* __restrict__ dd,
                             float* __restrict__ nu, float* __restrict__ mu_g) {
  int idx = blockIdx.x * 256 + threadIdx.x;
  if (idx >= BSZ * NXP) return;
  int b = idx / NXP, i = idx % NXP;
  p[idx]   = (i < NXDIM) ? -puz[b * NXDIM + i] : 0.0f;
  z[idx]   = 1.0f;
  lam[idx] = 1.0f;
  dd[idx]  = 0.0f;             // pads (i>=729) must stay 0 for k_adat
  if (i < MP) nu[b * MP + i] = 0.0f;
  if (i == 0) mu_g[b] = 1.0f;  // mean(z0*lam0) = 1
}

__global__ void k_setupB(const float* __restrict__ A32,
                         const float* __restrict__ lz, float* __restrict__ bvec) {
  int m = blockIdx.x, tid = threadIdx.x;
  __shared__ float red[256];
  float s = 0.0f;
  for (int i = tid; i < NXDIM; i += 256)
    s += A32[m * NXP + i] * expf(lz[i]);
  red[tid] = s; __syncthreads();
  for (int w = 128; w > 0; w >>= 1) { if (tid < w) red[tid] += red[tid + w]; __syncthreads(); }
  if (tid == 0) bvec[m] = red[0];
}

// ---------------- per-iteration kernels ----------------

// Fused stage1 (rz,rc,d,g) + rhs (mu comes from k_post / setup). One WG per batch.
__global__ __launch_bounds__(1024) void k_pre(const float* __restrict__ A32,
                                              const float* __restrict__ AT32,
                                              const float* __restrict__ z,
                                              const float* __restrict__ lam,
                                              const float* __restrict__ nu,
                                              const float* __restrict__ p,
                                              const float* __restrict__ bvec,
                                              const float* __restrict__ mu_g,
                                              float* __restrict__ dd,
                                              float* __restrict__ g,
                                              float* __restrict__ rhs) {
  int b = blockIdx.x, tid = threadIdx.x;
  __shared__ float nus[MDIM];
  __shared__ float zs[NXP];
  __shared__ float dgs[NXP];
  for (int l = tid; l < NXP; l += CTHR) {
    zs[l]  = (l < NXDIM) ? z[b * NXP + l] : 0.0f;
    dgs[l] = 0.0f;
  }
  for (int l = tid; l < MDIM; l += CTHR) nus[l] = nu[b * MP + l];
  __syncthreads();
  float muv = mu_g[b];
  if (tid < NXDIM) {
    int i = tid;
    float a0 = 0.0f, a1 = 0.0f, a2 = 0.0f, a3 = 0.0f;
    #pragma unroll 1
    for (int m = 0; m < MDIM; m += 4) {      // 324 % 4 == 0
      a0 += A32[(m + 0) * NXP + i] * nus[m + 0];
      a1 += A32[(m + 1) * NXP + i] * nus[m + 1];
      a2 += A32[(m + 2) * NXP + i] * nus[m + 2];
      a3 += A32[(m + 3) * NXP + i] * nus[m + 3];
    }
    float acc = (a0 + a1) + (a2 + a3);
    float zv = zs[i], lv = lam[b * NXP + i], pv = p[b * NXP + i];
    float rz = EPSF * zv + pv - lv + acc;
    float rc = zv * lv - SIGF * muv;
    float ddv = 1.0f / (EPSF + lv / zv);
    float gv = -(rz + rc / zv);
    dd[b * NXP + i] = ddv;
    g[b * NXP + i]  = gv;
    dgs[i] = ddv * gv;
  }
  __syncthreads();
  if (tid < MDIM) {
    float s0 = 0.0f, s1 = 0.0f, s2 = 0.0f, s3 = 0.0f;  // a1-dot (z)
    float t0 = 0.0f, t1 = 0.0f, t2 = 0.0f, t3 = 0.0f;  // a2-dot (dg)
    #pragma unroll 1
    for (int i = 0; i < NXP; i += 4) {       // 736 % 4 == 0; pads are zero
      float w0 = AT32[(size_t)(i + 0) * MP + tid];
      float w1 = AT32[(size_t)(i + 1) * MP + tid];
      float w2 = AT32[(size_t)(i + 2) * MP + tid];
      float w3 = AT32[(size_t)(i + 3) * MP + tid];
      s0 += w0 * zs[i + 0];  t0 += w0 * dgs[i + 0];
      s1 += w1 * zs[i + 1];  t1 += w1 * dgs[i + 1];
      s2 += w2 * zs[i + 2];  t2 += w2 * dgs[i + 2];
      s3 += w3 * zs[i + 3];  t3 += w3 * dgs[i + 3];
    }
    rhs[b * MP + tid] = ((t0 + t1) + (t2 + t3)) + ((s0 + s1) + (s2 + s3)) - bvec[tid];
  }
}

// ADAT[b] upper 64x64 tile pairs, vector f32 FMA. Block = 256 thr, 4x4/thread,
// strided ownership: rows {ty+16r}, cols {tx+16c} -> conflict-free LDS reads.
__global__ __launch_bounds__(256) void k_adat(const float* __restrict__ A32,
                                              const float* __restrict__ dd,
                                              float* __restrict__ ADAT) {
  int pr = blockIdx.x;   // 0..20 upper tile pairs of 6x6 tiling
  int b  = blockIdx.y;
  int ti = 0, prr = pr;
  while (prr >= 6 - ti) { prr -= 6 - ti; ti++; }
  int tj = ti + prr;
  int m0 = ti * 64, n0 = tj * 64;
  __shared__ float Sa[AKC][66];   // [k][row] transposed
  __shared__ float Sb[AKC][66];
  int tid = threadIdx.x;
  int tx = tid & 15, ty = tid >> 4;
  const float* db = dd + b * NXP;
  float acc[4][4];
  #pragma unroll
  for (int r = 0; r < 4; ++r)
    #pragma unroll
    for (int c = 0; c < 4; ++c) acc[r][c] = 0.0f;

  #pragma unroll 1
  for (int ch = 0; ch < ANCH; ++ch) {
    int i0 = ch * AKC;
    __syncthreads();
    #pragma unroll
    for (int q = 0; q < 4; ++q) {
      int row = ty + q * 16;
      int mrow = m0 + row, nrow = n0 + row;
      Sa[tx][row] = (mrow < MDIM) ? A32[(size_t)mrow * NXP + i0 + tx] : 0.0f;
      Sb[tx][row] = (nrow < MDIM) ? A32[(size_t)nrow * NXP + i0 + tx] * db[i0 + tx] : 0.0f;
    }
    __syncthreads();
    #pragma unroll
    for (int k = 0; k < AKC; ++k) {
      float ra[4], rb[4];
      #pragma unroll
      for (int r = 0; r < 4; ++r) ra[r] = Sa[k][ty + 16 * r];
      #pragma unroll
      for (int c = 0; c < 4; ++c) rb[c] = Sb[k][tx + 16 * c];
      #pragma unroll
      for (int r = 0; r < 4; ++r)
        #pragma unroll
        for (int c = 0; c < 4; ++c) acc[r][c] += ra[r] * rb[c];
    }
  }
  float* Mb = ADAT + (size_t)b * LDA * LDA;
  #pragma unroll
  for (int r = 0; r < 4; ++r) {
    int m = m0 + ty + 16 * r;
    if (m >= MDIM) continue;
    #pragma unroll
    for (int c = 0; c < 4; ++c) {
      int n = n0 + tx + 16 * c;
      if (n < MDIM) Mb[(size_t)m * LDA + n] = acc[r][c];
    }
  }
}

// Blocked upper Cholesky (U^T U) + solve, one 1024-thread WG (16 waves) per batch.
// NB=36 (9 panels) with the PROVEN static-index idiom (pragma unroll + if(t<r)).
__global__ __launch_bounds__(1024) void k_chol(float* __restrict__ ADAT,
                                               const float* __restrict__ rhs,
                                               float* __restrict__ dnu) {
  int b = blockIdx.x, tid = threadIdx.x;
  int lane = tid & 63, wid = tid >> 6;      // 16 waves
  float* Mb = ADAT + (size_t)b * LDA * LDA;
  __shared__ float P[NB][PSTR];   // panel rows U[k0+t][j], abs col idx; [324,356) zero
  __shared__ float D[NB][NB + 1]; // diagonal block
  __shared__ float yv[MDIM];      // rhs -> y -> x
  __shared__ float ivp[NB];
  __shared__ float ys[NB];

  for (int l = tid; l < NB * (PSTR - MDIM); l += CTHR) {
    int r = l / (PSTR - MDIM), c = l % (PSTR - MDIM);
    P[r][MDIM + c] = 0.0f;         // zero pad columns once; never written again
  }
  for (int l = tid; l < MDIM; l += CTHR) yv[l] = rhs[b * MP + l];

  #pragma unroll 1
  for (int p = 0; p < NPAN; ++p) {
    int k0 = p * NB, t0 = k0 + NB, rem = MDIM - t0;
    __syncthreads();
    // ---- load diag block cooperatively (NB*NB = 1296 > 1024: strided loop) ----
    for (int l = tid; l < NB * NB; l += CTHR) {
      int r = l / NB, c = l % NB;
      D[r][c] = Mb[(size_t)(k0 + r) * LDA + (k0 + c)];
    }
    __syncthreads();
    // ---- factor diag block: wave 0, shfl recurrence (static kk via full unroll) ----
    if (wid == 0) {
      float dreg[NB];
      #pragma unroll
      for (int r = 0; r < NB; ++r) dreg[r] = (lane < NB) ? D[r][lane] : 0.0f;
      float myiv = 0.0f;
      #pragma unroll
      for (int kk = 0; kk < NB; ++kk) {
        float dk = __shfl(dreg[kk], kk);
        float iv = 1.0f / sqrtf(dk);
        float u  = dreg[kk] * iv;      // row kk scaled: U[kk][lane]
        dreg[kk] = u;
        if (lane == kk) myiv = iv;
        #pragma unroll
        for (int r = kk + 1; r < NB; ++r)
          dreg[r] -= __shfl(u, r) * u; // rank-1: D[r][lane] -= U[kk][r]*U[kk][lane]
      }
      if (lane < NB) {
        ivp[lane] = myiv;
        #pragma unroll
        for (int r = 0; r < NB; ++r) {
          D[r][lane] = dreg[r];
          if (r <= lane) Mb[(size_t)(k0 + r) * LDA + (k0 + lane)] = dreg[r];
        }
      }
    }
    __syncthreads();
    // ---- panel rows (triangular solves, static val[] indexing) + fused y col ----
    {
      bool isY = (tid == rem);
      bool act = (tid < rem) || isY;
      int j = t0 + tid;
      if (act) {
        float val[NB];
        #pragma unroll
        for (int r = 0; r < NB; ++r) {
          float v = isY ? yv[k0 + r] : Mb[(size_t)(k0 + r) * LDA + j];
          #pragma unroll
          for (int t = 0; t < NB; ++t)
            if (t < r) v -= D[t][r] * val[t];
          v *= ivp[r];
          val[r] = v;
          if (isY) { ys[r] = v; yv[k0 + r] = v; }
          else     { P[r][j] = v; Mb[(size_t)(k0 + r) * LDA + j] = v; }
        }
      }
    }
    __syncthreads();
    if (rem <= 0) continue;
    // ---- y tail update ----
    if (tid < rem) {
      int j = t0 + tid;
      float s = yv[j];
      #pragma unroll
      for (int t = 0; t < NB; ++t) s -= P[t][j] * ys[t];
      yv[j] = s;
    }
    // ---- trailing update: 32x32 tile per wave, 4x4 regs per lane ----
    {
      int Ni = (rem + 31) >> 5;
      int cnt = Ni * (Ni + 1) / 2;
      for (int tt = wid; tt < cnt; tt += 16) {
        int a = 0, r2 = tt;
        while (r2 >= Ni - a) { r2 -= Ni - a; ++a; }
        int bb = a + r2;
        int i0 = t0 + 32 * a, j0 = t0 + 32 * bb;
        int ib = i0 + (lane >> 3);   // rows ib + 8r
        int jb = j0 + (lane & 7);    // cols jb + 8c
        bool full = (i0 + 31 < MDIM) && (j0 + 31 < MDIM);
        float cv[4][4];
        if (full) {
          #pragma unroll
          for (int r = 0; r < 4; ++r)
            #pragma unroll
            for (int c = 0; c < 4; ++c)
              cv[r][c] = Mb[(size_t)(ib + 8 * r) * LDA + (jb + 8 * c)];
        } else {
          #pragma unroll
          for (int r = 0; r < 4; ++r)
            #pragma unroll
            for (int c = 0; c < 4; ++c) {
              int i = ib + 8 * r, j = jb + 8 * c;
              cv[r][c] = (i < MDIM && j < MDIM) ? Mb[(size_t)i * LDA + j] : 0.0f;
            }
        }
        #pragma unroll
        for (int t = 0; t < NB; ++t) {
          float pi[4], pj[4];
          #pragma unroll
          for (int r = 0; r < 4; ++r) pi[r] = P[t][ib + 8 * r];
          #pragma unroll
          for (int c = 0; c < 4; ++c) pj[c] = P[t][jb + 8 * c];
          #pragma unroll
          for (int r = 0; r < 4; ++r)
            #pragma unroll
            for (int c = 0; c < 4; ++c) cv[r][c] -= pi[r] * pj[c];
        }
        if (full && bb > a) {        // strictly upper tile: unguarded store
          #pragma unroll
          for (int r = 0; r < 4; ++r)
            #pragma unroll
            for (int c = 0; c < 4; ++c)
              Mb[(size_t)(ib + 8 * r) * LDA + (jb + 8 * c)] = cv[r][c];
        } else {
          #pragma unroll
          for (int r = 0; r < 4; ++r)
            #pragma unroll
            for (int c = 0; c < 4; ++c) {
              int i = ib + 8 * r, j = jb + 8 * c;
              if (i < MDIM && j < MDIM && j >= i) Mb[(size_t)i * LDA + j] = cv[r][c];
            }
        }
      }
    }
  }
  // ---- back substitution: U x = y ----
  #pragma unroll 1
  for (int p = NPAN - 1; p >= 0; --p) {
    int k0 = p * NB, t0 = k0 + NB;
    __syncthreads();
    for (int l = tid; l < NB * NB; l += CTHR) {
      int r = l / NB, c = l % NB;
      D[r][c] = Mb[(size_t)(k0 + r) * LDA + (k0 + c)];
    }
    __syncthreads();
    if (t0 < MDIM) {  // y[k0+r] -= sum_{j>=t0} U[k0+r][j] * x[j]
      for (int r = wid; r < NB; r += 16) {
        float s = 0.0f;
        for (int j = t0 + lane; j < MDIM; j += 64)
          s += Mb[(size_t)(k0 + r) * LDA + j] * yv[j];
        for (int off = 32; off > 0; off >>= 1) s += __shfl_xor(s, off);
        if (lane == 0) yv[k0 + r] -= s;
      }
    }
    __syncthreads();
    if (tid < 64) {   // wave-0 shfl-based diagonal back-solve (lanes 0..35)
      float accv = 0.0f;
      for (int kk = NB - 1; kk >= 0; --kk) {
        float ad = __shfl(accv, kk);
        float xkk = (yv[k0 + kk] - ad) / D[kk][kk];
        if (lane < kk) accv += D[lane][kk] * xkk;
        if (lane == kk) yv[k0 + kk] = xkk;
      }
    }
  }
  __syncthreads();
  for (int l = tid; l < MDIM; l += CTHR) dnu[b * MP + l] = yv[l];
}

// Fused step+update+next-mu: dz/dlam in registers, in-WG alpha reduction, apply,
// then mu_{t+1} = mean(z_new * lam_new) for the next k_pre.
__global__ __launch_bounds__(1024) void k_post(const float* __restrict__ A32,
                                               const float* __restrict__ dnu,
                                               const float* __restrict__ dd,
                                               const float* __restrict__ g,
                                               float* __restrict__ mu_g,
                                               float* __restrict__ z,
                                               float* __restrict__ lam,
                                               float* __restrict__ nu) {
  int b = blockIdx.x, tid = threadIdx.x;
  int lane = tid & 63, wid = tid >> 6;
  __shared__ float ds[MDIM];
  __shared__ float wred[16];
  __shared__ float salpha;
  for (int l = tid; l < MDIM; l += CTHR) ds[l] = dnu[b * MP + l];
  __syncthreads();
  float muv = mu_g[b];
  float zv = 0.0f, lv = 0.0f, dzv = 0.0f, dlv = 0.0f;
  bool act = (tid < NXDIM);
  float inf = __builtin_inff();
  float rm = inf;
  if (act) {
    int i = tid;
    float a0 = 0.0f, a1 = 0.0f, a2 = 0.0f, a3 = 0.0f;
    #pragma unroll 1
    for (int m = 0; m < MDIM; m += 4) {
      a0 += A32[(m + 0) * NXP + i] * ds[m + 0];
      a1 += A32[(m + 1) * NXP + i] * ds[m + 1];
      a2 += A32[(m + 2) * NXP + i] * ds[m + 2];
      a3 += A32[(m + 3) * NXP + i] * ds[m + 3];
    }
    float acc = (a0 + a1) + (a2 + a3);
    zv = z[b * NXP + i]; lv = lam[b * NXP + i];
    float ddv = dd[b * NXP + i], gv = g[b * NXP + i];
    dzv = ddv * (gv - acc);
    float rc = zv * lv - SIGF * muv;
    dlv = -(rc + lv * dzv) / zv;
    float r1 = (dzv < 0.0f) ? (-zv / dzv) : inf;
    float r2 = (dlv < 0.0f) ? (-lv / dlv) : inf;
    rm = fminf(r1, r2);
  }
  for (int off = 32; off > 0; off >>= 1) rm = fminf(rm, __shfl_xor(rm, off));
  if (lane == 0) wred[wid] = rm;
  __syncthreads();
  if (tid == 0) {
    float a = wred[0];
    #pragma unroll
    for (int w = 1; w < 16; ++w) a = fminf(a, wred[w]);
    salpha = fminf(1.0f, 0.99f * a);
  }
  __syncthreads();
  float a = salpha;
  float zn = zv + a * dzv, ln = lv + a * dlv;
  if (act) {
    z[b * NXP + tid]   = zn;
    lam[b * NXP + tid] = ln;
  }
  if (tid < MDIM) nu[b * MP + tid] += a * ds[tid];
  // ---- next-iteration mu = mean(z_new * lam_new) ----
  float s = act ? zn * ln : 0.0f;
  for (int off = 32; off > 0; off >>= 1) s += __shfl_xor(s, off);
  __syncthreads();                 // wred reuse
  if (lane == 0) wred[wid] = s;
  __syncthreads();
  if (tid == 0) {
    float t = 0.0f;
    #pragma unroll
    for (int w = 0; w < 16; ++w) t += wred[w];
    mu_g[b] = t / (float)NXDIM;
  }
}

__global__ void k_out(const float* __restrict__ z, float* __restrict__ out) {
  int idx = blockIdx.x * 256 + threadIdx.x;
  if (idx >= BSZ * NXDIM) return;
  int b = idx / NXDIM, i = idx % NXDIM;
  out[idx] = z[b * NXP + i];
}

// ---------------- host launcher ----------------

extern "C" void kernel_launch(void* const* d_in, const int* in_sizes, int n_in,
                              void* d_out, int out_size, void* d_ws, size_t ws_size,
                              hipStream_t stream) {
  const float* puz = (const float*)d_in[0];
  const float* Af  = (const float*)d_in[1];
  const float* lz  = (const float*)d_in[2];
  float* out = (float*)d_out;

  char* base = (char*)d_ws;
  size_t off = 0;
  auto alloc = [&](size_t bytes) -> void* {
    void* ptr = base + off;
    off = (off + bytes + 255) & ~(size_t)255;
    return ptr;
  };
  float* A32  = (float*)alloc((size_t)MDIM * NXP * 4);
  float* AT32 = (float*)alloc((size_t)NXP * MP * 4);
  float* p_   = (float*)alloc((size_t)BSZ * NXP * 4);
  float* z_   = (float*)alloc((size_t)BSZ * NXP * 4);
  float* lam_ = (float*)alloc((size_t)BSZ * NXP * 4);
  float* dd_  = (float*)alloc((size_t)BSZ * NXP * 4);
  float* g_   = (float*)alloc((size_t)BSZ * NXP * 4);
  float* nu_  = (float*)alloc((size_t)BSZ * MP * 4);
  float* dnu_ = (float*)alloc((size_t)BSZ * MP * 4);
  float* rhs_ = (float*)alloc((size_t)BSZ * MP * 4);
  float* bvec = (float*)alloc((size_t)MP * 4);
  float* mu_  = (float*)alloc((size_t)BSZ * 4);
  float* ADAT = (float*)alloc((size_t)BSZ * LDA * LDA * 4);
  (void)ws_size; (void)in_sizes; (void)n_in; (void)out_size;

  k_setupA<<<943, 256, 0, stream>>>(Af, A32, AT32);
  k_setupState<<<184, 256, 0, stream>>>(puz, p_, z_, lam_, dd_, nu_, mu_);
  k_setupB<<<324, 256, 0, stream>>>(A32, lz, bvec);

  dim3 g4(21, 64);
  for (int it = 0; it < NIT; ++it) {
    k_pre<<<64, CTHR, 0, stream>>>(A32, AT32, z_, lam_, nu_, p_, bvec, mu_, dd_, g_, rhs_);
    k_adat<<<g4, 256, 0, stream>>>(A32, dd_, ADAT);
    k_chol<<<64, CTHR, 0, stream>>>(ADAT, rhs_, dnu_);
    k_post<<<64, CTHR, 0, stream>>>(A32, dnu_, dd_, g_, mu_, z_, lam_, nu_);
  }
  k_out<<<183, 256, 0, stream>>>(z_, out);
}

// Round 10
// 16703.972 us; speedup vs baseline: 1.2646x; 1.2646x over previous
//
#include <hip/hip_runtime.h>
#include <math.h>

// ---------------- problem constants ----------------
#define BSZ   64
#define NXDIM 729
#define NXP   736          // padded (multiple of 16), pad cols are zero
#define MDIM  324
#define MP    328          // padded vector length for m-dim arrays
#define LDA   328          // ADAT leading dim (floats)
#define EPSF  0.1f
#define SIGF  0.1f
#define NIT   30

// Cholesky blocking (NB=18 measured optimum: r8=292us, r9 NB=36=428us)
#define NB    18
#define NPAN  18           // 324 / 18
#define CTHR  1024
#define PSTR  356          // P panel stride: 324 + 32 zero pad (tile reads overshoot <= +30)

// ADAT tiling: 64x64 tiles over 6x6 upper -> 21 pairs, vector f32 FMA
#define AKC   16
#define ANCH  46           // 736 / 16

typedef unsigned long long ull;

// ---------------- setup kernels ----------------

__global__ void k_setupA(const float* __restrict__ Af,
                         float* __restrict__ A32, float* __restrict__ AT32) {
  int idx = blockIdx.x * 256 + threadIdx.x;
  if (idx < MDIM * NXP) {
    int r = idx / NXP, c = idx % NXP;
    A32[idx] = (c < NXDIM) ? Af[r * NXDIM + c] : 0.0f;
  }
  if (idx < NXP * MP) {
    int i = idx / MP, m = idx % MP;
    AT32[idx] = (i < NXDIM && m < MDIM) ? Af[m * NXDIM + i] : 0.0f;
  }
}

__global__ void k_setupState(const float* __restrict__ puz,
                             float* __restrict__ p, float* __restrict__ z,
                             float* __restrict__ lam, float* __restrict__ dd,
                             float* __restrict__ nu, float* __restrict__ mu_g,
                             float* __restrict__ atnu) {
  int idx = blockIdx.x * 256 + threadIdx.x;
  if (idx >= BSZ * NXP) return;
  int b = idx / NXP, i = idx % NXP;
  p[idx]    = (i < NXDIM) ? -puz[b * NXDIM + i] : 0.0f;
  z[idx]    = 1.0f;
  lam[idx]  = 1.0f;
  dd[idx]   = 0.0f;            // pads (i>=729) must stay 0 for k_adat
  atnu[idx] = 0.0f;            // A^T nu0 = 0 (nu0 = 0)
  if (i < MP) nu[b * MP + i] = 0.0f;
  if (i == 0) mu_g[b] = 1.0f;  // mean(z0*lam0) = 1
}

__global__ void k_setupB(const float* __restrict__ A32,
                         const float* __restrict__ lz, float* __restrict__ bvec) {
  int m = blockIdx.x, tid = threadIdx.x;
  __shared__ float red[256];
  float s = 0.0f;
  for (int i = tid; i < NXDIM; i += 256)
    s += A32[m * NXP + i] * expf(lz[i]);
  red[tid] = s; __syncthreads();
  for (int w = 128; w > 0; w >>= 1) { if (tid < w) red[tid] += red[tid + w]; __syncthreads(); }
  if (tid == 0) bvec[m] = red[0];
}

// ---------------- per-iteration kernels ----------------

// Initial pre (runs once): stage1 (rz,rc,d,g) + rhs from initial state.
__global__ __launch_bounds__(1024) void k_pre0(const float* __restrict__ A32,
                                               const float* __restrict__ AT32,
                                               const float* __restrict__ z,
                                               const float* __restrict__ lam,
                                               const float* __restrict__ nu,
                                               const float* __restrict__ p,
                                               const float* __restrict__ bvec,
                                               const float* __restrict__ mu_g,
                                               float* __restrict__ dd,
                                               float* __restrict__ g,
                                               float* __restrict__ rhs) {
  int b = blockIdx.x, tid = threadIdx.x;
  __shared__ float nus[MDIM];
  __shared__ float zs[NXP];
  __shared__ float dgs[NXP];
  for (int l = tid; l < NXP; l += CTHR) {
    zs[l]  = (l < NXDIM) ? z[b * NXP + l] : 0.0f;
    dgs[l] = 0.0f;
  }
  for (int l = tid; l < MDIM; l += CTHR) nus[l] = nu[b * MP + l];
  __syncthreads();
  float muv = mu_g[b];
  if (tid < NXDIM) {
    int i = tid;
    float a0 = 0.0f, a1 = 0.0f, a2 = 0.0f, a3 = 0.0f;
    #pragma unroll 1
    for (int m = 0; m < MDIM; m += 4) {      // 324 % 4 == 0
      a0 += A32[(m + 0) * NXP + i] * nus[m + 0];
      a1 += A32[(m + 1) * NXP + i] * nus[m + 1];
      a2 += A32[(m + 2) * NXP + i] * nus[m + 2];
      a3 += A32[(m + 3) * NXP + i] * nus[m + 3];
    }
    float acc = (a0 + a1) + (a2 + a3);
    float zv = zs[i], lv = lam[b * NXP + i], pv = p[b * NXP + i];
    float rz = EPSF * zv + pv - lv + acc;
    float rc = zv * lv - SIGF * muv;
    float ddv = 1.0f / (EPSF + lv / zv);
    float gv = -(rz + rc / zv);
    dd[b * NXP + i] = ddv;
    g[b * NXP + i]  = gv;
    dgs[i] = ddv * gv;
  }
  __syncthreads();
  if (tid < MDIM) {
    float s0 = 0.0f, s1 = 0.0f, s2 = 0.0f, s3 = 0.0f;
    float t0 = 0.0f, t1 = 0.0f, t2 = 0.0f, t3 = 0.0f;
    #pragma unroll 1
    for (int i = 0; i < NXP; i += 4) {       // 736 % 4 == 0; pads are zero
      float w0 = AT32[(size_t)(i + 0) * MP + tid];
      float w1 = AT32[(size_t)(i + 1) * MP + tid];
      float w2 = AT32[(size_t)(i + 2) * MP + tid];
      float w3 = AT32[(size_t)(i + 3) * MP + tid];
      s0 += w0 * zs[i + 0];  t0 += w0 * dgs[i + 0];
      s1 += w1 * zs[i + 1];  t1 += w1 * dgs[i + 1];
      s2 += w2 * zs[i + 2];  t2 += w2 * dgs[i + 2];
      s3 += w3 * zs[i + 3];  t3 += w3 * dgs[i + 3];
    }
    rhs[b * MP + tid] = ((t0 + t1) + (t2 + t3)) + ((s0 + s1) + (s2 + s3)) - bvec[tid];
  }
}

// ADAT[b] upper 64x64 tile pairs, vector f32 FMA. Block = 256 thr, 4x4/thread,
// strided ownership: rows {ty+16r}, cols {tx+16c} -> conflict-free LDS reads.
__global__ __launch_bounds__(256) void k_adat(const float* __restrict__ A32,
                                              const float* __restrict__ dd,
                                              float* __restrict__ ADAT) {
  int pr = blockIdx.x;   // 0..20 upper tile pairs of 6x6 tiling
  int b  = blockIdx.y;
  int ti = 0, prr = pr;
  while (prr >= 6 - ti) { prr -= 6 - ti; ti++; }
  int tj = ti + prr;
  int m0 = ti * 64, n0 = tj * 64;
  __shared__ float Sa[AKC][66];   // [k][row] transposed
  __shared__ float Sb[AKC][66];
  int tid = threadIdx.x;
  int tx = tid & 15, ty = tid >> 4;
  const float* db = dd + b * NXP;
  float acc[4][4];
  #pragma unroll
  for (int r = 0; r < 4; ++r)
    #pragma unroll
    for (int c = 0; c < 4; ++c) acc[r][c] = 0.0f;

  #pragma unroll 1
  for (int ch = 0; ch < ANCH; ++ch) {
    int i0 = ch * AKC;
    __syncthreads();
    #pragma unroll
    for (int q = 0; q < 4; ++q) {
      int row = ty + q * 16;
      int mrow = m0 + row, nrow = n0 + row;
      Sa[tx][row] = (mrow < MDIM) ? A32[(size_t)mrow * NXP + i0 + tx] : 0.0f;
      Sb[tx][row] = (nrow < MDIM) ? A32[(size_t)nrow * NXP + i0 + tx] * db[i0 + tx] : 0.0f;
    }
    __syncthreads();
    #pragma unroll
    for (int k = 0; k < AKC; ++k) {
      float ra[4], rb[4];
      #pragma unroll
      for (int r = 0; r < 4; ++r) ra[r] = Sa[k][ty + 16 * r];
      #pragma unroll
      for (int c = 0; c < 4; ++c) rb[c] = Sb[k][tx + 16 * c];
      #pragma unroll
      for (int r = 0; r < 4; ++r)
        #pragma unroll
        for (int c = 0; c < 4; ++c) acc[r][c] += ra[r] * rb[c];
    }
  }
  float* Mb = ADAT + (size_t)b * LDA * LDA;
  #pragma unroll
  for (int r = 0; r < 4; ++r) {
    int m = m0 + ty + 16 * r;
    if (m >= MDIM) continue;
    #pragma unroll
    for (int c = 0; c < 4; ++c) {
      int n = n0 + tx + 16 * c;
      if (n < MDIM) Mb[(size_t)m * LDA + n] = acc[r][c];
    }
  }
}

// Blocked upper Cholesky (U^T U) + solve, one 1024-thread WG (16 waves) per batch.
// NB=18, fully-unrolled static-indexed recurrences (round-8 version, 292us measured).
__global__ __launch_bounds__(1024) void k_chol(float* __restrict__ ADAT,
                                               const float* __restrict__ rhs,
                                               float* __restrict__ dnu) {
  int b = blockIdx.x, tid = threadIdx.x;
  int lane = tid & 63, wid = tid >> 6;      // 16 waves
  float* Mb = ADAT + (size_t)b * LDA * LDA;
  __shared__ float P[NB][PSTR];   // panel rows U[k0+t][j], abs col idx; [324,356) zero
  __shared__ float D[NB][NB + 1]; // diagonal block
  __shared__ float yv[MDIM];      // rhs -> y -> x
  __shared__ float ivp[NB];
  __shared__ float ys[NB];

  for (int l = tid; l < NB * (PSTR - MDIM); l += CTHR) {
    int r = l / (PSTR - MDIM), c = l % (PSTR - MDIM);
    P[r][MDIM + c] = 0.0f;         // zero pad columns once; never written again
  }
  for (int l = tid; l < MDIM; l += CTHR) yv[l] = rhs[b * MP + l];

  #pragma unroll 1
  for (int p = 0; p < NPAN; ++p) {
    int k0 = p * NB, t0 = k0 + NB, rem = MDIM - t0;
    __syncthreads();
    // ---- load diag block cooperatively ----
    if (tid < NB * NB) {
      int r = tid / NB, c = tid % NB;
      D[r][c] = Mb[(size_t)(k0 + r) * LDA + (k0 + c)];
    }
    __syncthreads();
    // ---- factor diag block: wave 0, shfl recurrence (no barriers inside) ----
    if (wid == 0) {
      float dreg[NB];
      #pragma unroll
      for (int r = 0; r < NB; ++r) dreg[r] = (lane < NB) ? D[r][lane] : 0.0f;
      float myiv = 0.0f;
      #pragma unroll
      for (int kk = 0; kk < NB; ++kk) {
        float dk = __shfl(dreg[kk], kk);
        float iv = 1.0f / sqrtf(dk);
        float u  = dreg[kk] * iv;      // row kk scaled: U[kk][lane]
        dreg[kk] = u;
        if (lane == kk) myiv = iv;
        #pragma unroll
        for (int r = kk + 1; r < NB; ++r)
          dreg[r] -= __shfl(u, r) * u; // rank-1: D[r][lane] -= U[kk][r]*U[kk][lane]
      }
      if (lane < NB) {
        ivp[lane] = myiv;
        #pragma unroll
        for (int r = 0; r < NB; ++r) {
          D[r][lane] = dreg[r];
          if (r <= lane) Mb[(size_t)(k0 + r) * LDA + (k0 + lane)] = dreg[r];
        }
      }
    }
    __syncthreads();
    // ---- panel rows (triangular solves, barrier-free) + fused fwd-subst col ----
    {
      bool isY = (tid == rem);
      bool act = (tid < rem) || isY;
      int j = t0 + tid;
      if (act) {
        float val[NB];
        #pragma unroll
        for (int r = 0; r < NB; ++r) {
          float v = isY ? yv[k0 + r] : Mb[(size_t)(k0 + r) * LDA + j];
          #pragma unroll
          for (int t = 0; t < NB; ++t)
            if (t < r) v -= D[t][r] * val[t];
          v *= ivp[r];
          val[r] = v;
          if (isY) { ys[r] = v; yv[k0 + r] = v; }
          else     { P[r][j] = v; Mb[(size_t)(k0 + r) * LDA + j] = v; }
        }
      }
    }
    __syncthreads();
    if (rem <= 0) continue;
    // ---- y tail update ----
    if (tid < rem) {
      int j = t0 + tid;
      float s = yv[j];
      #pragma unroll
      for (int t = 0; t < NB; ++t) s -= P[t][j] * ys[t];
      yv[j] = s;
    }
    // ---- trailing update: 32x32 tile per wave, 4x4 regs per lane ----
    {
      int Ni = (rem + 31) >> 5;
      int cnt = Ni * (Ni + 1) / 2;
      for (int tt = wid; tt < cnt; tt += 16) {
        int a = 0, r2 = tt;
        while (r2 >= Ni - a) { r2 -= Ni - a; ++a; }
        int bb = a + r2;
        int i0 = t0 + 32 * a, j0 = t0 + 32 * bb;
        int ib = i0 + (lane >> 3);   // rows ib + 8r
        int jb = j0 + (lane & 7);    // cols jb + 8c
        bool full = (i0 + 31 < MDIM) && (j0 + 31 < MDIM);
        float cv[4][4];
        if (full) {
          #pragma unroll
          for (int r = 0; r < 4; ++r)
            #pragma unroll
            for (int c = 0; c < 4; ++c)
              cv[r][c] = Mb[(size_t)(ib + 8 * r) * LDA + (jb + 8 * c)];
        } else {
          #pragma unroll
          for (int r = 0; r < 4; ++r)
            #pragma unroll
            for (int c = 0; c < 4; ++c) {
              int i = ib + 8 * r, j = jb + 8 * c;
              cv[r][c] = (i < MDIM && j < MDIM) ? Mb[(size_t)i * LDA + j] : 0.0f;
            }
        }
        #pragma unroll
        for (int t = 0; t < NB; ++t) {
          float pi[4], pj[4];
          #pragma unroll
          for (int r = 0; r < 4; ++r) pi[r] = P[t][ib + 8 * r];
          #pragma unroll
          for (int c = 0; c < 4; ++c) pj[c] = P[t][jb + 8 * c];
          #pragma unroll
          for (int r = 0; r < 4; ++r)
            #pragma unroll
            for (int c = 0; c < 4; ++c) cv[r][c] -= pi[r] * pj[c];
        }
        if (full && bb > a) {        // strictly upper tile: unguarded store
          #pragma unroll
          for (int r = 0; r < 4; ++r)
            #pragma unroll
            for (int c = 0; c < 4; ++c)
              Mb[(size_t)(ib + 8 * r) * LDA + (jb + 8 * c)] = cv[r][c];
        } else {
          #pragma unroll
          for (int r = 0; r < 4; ++r)
            #pragma unroll
            for (int c = 0; c < 4; ++c) {
              int i = ib + 8 * r, j = jb + 8 * c;
              if (i < MDIM && j < MDIM && j >= i) Mb[(size_t)i * LDA + j] = cv[r][c];
            }
        }
      }
    }
  }
  // ---- back substitution: U x = y ----
  #pragma unroll 1
  for (int p = NPAN - 1; p >= 0; --p) {
    int k0 = p * NB, t0 = k0 + NB;
    __syncthreads();
    if (tid < NB * NB) {
      int r = tid / NB, c = tid % NB;
      D[r][c] = Mb[(size_t)(k0 + r) * LDA + (k0 + c)];
    }
    __syncthreads();
    if (t0 < MDIM) {  // y[k0+r] -= sum_{j>=t0} U[k0+r][j] * x[j]
      for (int r = wid; r < NB; r += 16) {
        float s = 0.0f;
        for (int j = t0 + lane; j < MDIM; j += 64)
          s += Mb[(size_t)(k0 + r) * LDA + j] * yv[j];
        for (int off = 32; off > 0; off >>= 1) s += __shfl_xor(s, off);
        if (lane == 0) yv[k0 + r] -= s;
      }
    }
    __syncthreads();
    if (tid < 64) {   // wave-0 shfl-based diagonal back-solve
      float accv = 0.0f;
      for (int kk = NB - 1; kk >= 0; --kk) {
        float ad = __shfl(accv, kk);
        float xkk = (yv[k0 + kk] - ad) / D[kk][kk];
        if (lane < kk) accv += D[lane][kk] * xkk;
        if (lane == kk) yv[k0 + kk] = xkk;
      }
    }
  }
  __syncthreads();
  for (int l = tid; l < MDIM; l += CTHR) dnu[b * MP + l] = yv[l];
}

// Fused post(t) + pre(t+1). Incremental atnu = A^T nu maintained exactly:
// atnu' = atnu + alpha * (A^T dnu), reusing the post-phase matvec acc.
__global__ __launch_bounds__(1024) void k_popre(const float* __restrict__ A32,
                                                const float* __restrict__ AT32,
                                                const float* __restrict__ dnu,
                                                const float* __restrict__ p,
                                                const float* __restrict__ bvec,
                                                float* __restrict__ mu_g,
                                                float* __restrict__ dd,
                                                float* __restrict__ g,
                                                float* __restrict__ atnu,
                                                float* __restrict__ z,
                                                float* __restrict__ lam,
                                                float* __restrict__ nu,
                                                float* __restrict__ rhs) {
  int b = blockIdx.x, tid = threadIdx.x;
  int lane = tid & 63, wid = tid >> 6;
  __shared__ float ds[MDIM];
  __shared__ float zs[NXP];
  __shared__ float dgs[NXP];
  __shared__ float wred[16];
  __shared__ float salpha, smu;
  for (int l = tid; l < MDIM; l += CTHR) ds[l] = dnu[b * MP + l];
  for (int l = tid; l < NXP; l += CTHR) {
    if (l >= NXDIM) { zs[l] = 0.0f; dgs[l] = 0.0f; }
  }
  __syncthreads();
  bool act = (tid < NXDIM);
  float inf = __builtin_inff();
  float muv = mu_g[b];
  float zv = 0.0f, lv = 0.0f, dzv = 0.0f, dlv = 0.0f, accv = 0.0f;
  float rm = inf;
  // ---- post phase: step directions + alpha candidates ----
  if (act) {
    int i = tid;
    float a0 = 0.0f, a1 = 0.0f, a2 = 0.0f, a3 = 0.0f;
    #pragma unroll 1
    for (int m = 0; m < MDIM; m += 4) {
      a0 += A32[(m + 0) * NXP + i] * ds[m + 0];
      a1 += A32[(m + 1) * NXP + i] * ds[m + 1];
      a2 += A32[(m + 2) * NXP + i] * ds[m + 2];
      a3 += A32[(m + 3) * NXP + i] * ds[m + 3];
    }
    accv = (a0 + a1) + (a2 + a3);
    zv = z[b * NXP + i]; lv = lam[b * NXP + i];
    float ddv = dd[b * NXP + i], gv = g[b * NXP + i];
    dzv = ddv * (gv - accv);
    float rc = zv * lv - SIGF * muv;
    dlv = -(rc + lv * dzv) / zv;
    float r1 = (dzv < 0.0f) ? (-zv / dzv) : inf;
    float r2 = (dlv < 0.0f) ? (-lv / dlv) : inf;
    rm = fminf(r1, r2);
  }
  for (int off = 32; off > 0; off >>= 1) rm = fminf(rm, __shfl_xor(rm, off));
  if (lane == 0) wred[wid] = rm;
  __syncthreads();
  if (tid == 0) {
    float a = wred[0];
    #pragma unroll
    for (int w = 1; w < 16; ++w) a = fminf(a, wred[w]);
    salpha = fminf(1.0f, 0.99f * a);
  }
  __syncthreads();
  float a = salpha;
  float zn = zv + a * dzv, ln = lv + a * dlv;
  float na = 0.0f;
  if (act) {
    z[b * NXP + tid]   = zn;
    lam[b * NXP + tid] = ln;
    zs[tid] = zn;
    na = atnu[b * NXP + tid] + a * accv;   // A^T nu incremental (exact algebra)
    atnu[b * NXP + tid] = na;
  }
  if (tid < MDIM) nu[b * MP + tid] += a * ds[tid];
  // ---- mu_{t+1} = mean(z_new * lam_new) ----
  float s = act ? zn * ln : 0.0f;
  for (int off = 32; off > 0; off >>= 1) s += __shfl_xor(s, off);
  if (lane == 0) wred[wid] = s;            // safe: alpha reads of wred were pre-barrier
  __syncthreads();
  if (tid == 0) {
    float t = 0.0f;
    #pragma unroll
    for (int w = 0; w < 16; ++w) t += wred[w];
    smu = t / (float)NXDIM;
    mu_g[b] = smu;
  }
  __syncthreads();
  float mun = smu;
  // ---- pre phase (iteration t+1): rz, rc, d, g ----
  if (act) {
    int i = tid;
    float rz = EPSF * zn + p[b * NXP + i] - ln + na;
    float rcn = zn * ln - SIGF * mun;
    float ddn = 1.0f / (EPSF + ln / zn);
    float gn = -(rz + rcn / zn);
    dd[b * NXP + i] = ddn;
    g[b * NXP + i]  = gn;
    dgs[i] = ddn * gn;
  }
  __syncthreads();
  // ---- rhs for next solve ----
  if (tid < MDIM) {
    float s0 = 0.0f, s1 = 0.0f, s2 = 0.0f, s3 = 0.0f;
    float t0 = 0.0f, t1 = 0.0f, t2 = 0.0f, t3 = 0.0f;
    #pragma unroll 1
    for (int i = 0; i < NXP; i += 4) {
      float w0 = AT32[(size_t)(i + 0) * MP + tid];
      float w1 = AT32[(size_t)(i + 1) * MP + tid];
      float w2 = AT32[(size_t)(i + 2) * MP + tid];
      float w3 = AT32[(size_t)(i + 3) * MP + tid];
      s0 += w0 * zs[i + 0];  t0 += w0 * dgs[i + 0];
      s1 += w1 * zs[i + 1];  t1 += w1 * dgs[i + 1];
      s2 += w2 * zs[i + 2];  t2 += w2 * dgs[i + 2];
      s3 += w3 * zs[i + 3];  t3 += w3 * dgs[i + 3];
    }
    rhs[b * MP + tid] = ((t0 + t1) + (t2 + t3)) + ((s0 + s1) + (s2 + s3)) - bvec[tid];
  }
}

__global__ void k_out(const float* __restrict__ z, float* __restrict__ out) {
  int idx = blockIdx.x * 256 + threadIdx.x;
  if (idx >= BSZ * NXDIM) return;
  int b = idx / NXDIM, i = idx % NXDIM;
  out[idx] = z[b * NXP + i];
}

// ---------------- host launcher ----------------

extern "C" void kernel_launch(void* const* d_in, const int* in_sizes, int n_in,
                              void* d_out, int out_size, void* d_ws, size_t ws_size,
                              hipStream_t stream) {
  const float* puz = (const float*)d_in[0];
  const float* Af  = (const float*)d_in[1];
  const float* lz  = (const float*)d_in[2];
  float* out = (float*)d_out;

  char* base = (char*)d_ws;
  size_t off = 0;
  auto alloc = [&](size_t bytes) -> void* {
    void* ptr = base + off;
    off = (off + bytes + 255) & ~(size_t)255;
    return ptr;
  };
  float* A32  = (float*)alloc((size_t)MDIM * NXP * 4);
  float* AT32 = (float*)alloc((size_t)NXP * MP * 4);
  float* p_   = (float*)alloc((size_t)BSZ * NXP * 4);
  float* z_   = (float*)alloc((size_t)BSZ * NXP * 4);
  float* lam_ = (float*)alloc((size_t)BSZ * NXP * 4);
  float* dd_  = (float*)alloc((size_t)BSZ * NXP * 4);
  float* g_   = (float*)alloc((size_t)BSZ * NXP * 4);
  float* atnu_= (float*)alloc((size_t)BSZ * NXP * 4);
  float* nu_  = (float*)alloc((size_t)BSZ * MP * 4);
  float* dnu_ = (float*)alloc((size_t)BSZ * MP * 4);
  float* rhs_ = (float*)alloc((size_t)BSZ * MP * 4);
  float* bvec = (float*)alloc((size_t)MP * 4);
  float* mu_  = (float*)alloc((size_t)BSZ * 4);
  float* ADAT = (float*)alloc((size_t)BSZ * LDA * LDA * 4);
  (void)ws_size; (void)in_sizes; (void)n_in; (void)out_size;

  k_setupA<<<943, 256, 0, stream>>>(Af, A32, AT32);
  k_setupState<<<184, 256, 0, stream>>>(puz, p_, z_, lam_, dd_, nu_, mu_, atnu_);
  k_setupB<<<324, 256, 0, stream>>>(A32, lz, bvec);

  dim3 g4(21, 64);
  k_pre0<<<64, CTHR, 0, stream>>>(A32, AT32, z_, lam_, nu_, p_, bvec, mu_, dd_, g_, rhs_);
  for (int it = 0; it < NIT; ++it) {
    k_adat<<<g4, 256, 0, stream>>>(A32, dd_, ADAT);
    k_chol<<<64, CTHR, 0, stream>>>(ADAT, rhs_, dnu_);
    k_popre<<<64, CTHR, 0, stream>>>(A32, AT32, dnu_, p_, bvec, mu_, dd_, g_,
                                     atnu_, z_, lam_, nu_, rhs_);
  }
  k_out<<<183, 256, 0, stream>>>(z_, out);
}

// Round 11
// 15607.426 us; speedup vs baseline: 1.3535x; 1.0703x over previous
//
#include <hip/hip_runtime.h>
#include <math.h>

// ---------------- problem constants ----------------
#define BSZ   64
#define NXDIM 729
#define NXP   736          // padded (multiple of 16), pad cols are zero
#define MDIM  324
#define MP    328          // padded vector length for m-dim arrays
#define LDA   328          // ADAT leading dim (floats)
#define EPSF  0.1f
#define SIGF  0.1f
#define NIT   30

// Cholesky blocking (NB=18 measured optimum: r8=292us, r9 NB=36=428us)
#define NB    18
#define NPAN  18           // 324 / 18
#define CTHR  1024
#define PSTR  356          // P panel stride: 324 + 32 zero pad (tile reads overshoot <= +30)

// ADAT tiling: 64x64 tiles over 6x6 upper -> 21 pairs, vector f32 FMA
#define AKC   16
#define ANCH  46           // 736 / 16

typedef unsigned long long ull;

// ---------------- setup kernels ----------------

__global__ void k_setupA(const float* __restrict__ Af,
                         float* __restrict__ A32, float* __restrict__ AT32) {
  int idx = blockIdx.x * 256 + threadIdx.x;
  if (idx < MDIM * NXP) {
    int r = idx / NXP, c = idx % NXP;
    A32[idx] = (c < NXDIM) ? Af[r * NXDIM + c] : 0.0f;
  }
  if (idx < NXP * MP) {
    int i = idx / MP, m = idx % MP;
    AT32[idx] = (i < NXDIM && m < MDIM) ? Af[m * NXDIM + i] : 0.0f;
  }
}

__global__ void k_setupState(const float* __restrict__ puz,
                             float* __restrict__ p, float* __restrict__ z,
                             float* __restrict__ lam, float* __restrict__ dd,
                             float* __restrict__ nu, float* __restrict__ mu_g,
                             float* __restrict__ atnu) {
  int idx = blockIdx.x * 256 + threadIdx.x;
  if (idx >= BSZ * NXP) return;
  int b = idx / NXP, i = idx % NXP;
  p[idx]    = (i < NXDIM) ? -puz[b * NXDIM + i] : 0.0f;
  z[idx]    = 1.0f;
  lam[idx]  = 1.0f;
  dd[idx]   = 0.0f;            // pads (i>=729) must stay 0 for k_adat
  atnu[idx] = 0.0f;            // A^T nu0 = 0 (nu0 = 0)
  if (i < MP) nu[b * MP + i] = 0.0f;
  if (i == 0) mu_g[b] = 1.0f;  // mean(z0*lam0) = 1
}

__global__ void k_setupB(const float* __restrict__ A32,
                         const float* __restrict__ lz, float* __restrict__ bvec) {
  int m = blockIdx.x, tid = threadIdx.x;
  __shared__ float red[256];
  float s = 0.0f;
  for (int i = tid; i < NXDIM; i += 256)
    s += A32[m * NXP + i] * expf(lz[i]);
  red[tid] = s; __syncthreads();
  for (int w = 128; w > 0; w >>= 1) { if (tid < w) red[tid] += red[tid + w]; __syncthreads(); }
  if (tid == 0) bvec[m] = red[0];
}

// ---------------- per-iteration kernels ----------------

// Initial pre (runs once): stage1 (rz,rc,d,g) + rhs from initial state.
__global__ __launch_bounds__(1024) void k_pre0(const float* __restrict__ A32,
                                               const float* __restrict__ AT32,
                                               const float* __restrict__ z,
                                               const float* __restrict__ lam,
                                               const float* __restrict__ nu,
                                               const float* __restrict__ p,
                                               const float* __restrict__ bvec,
                                               const float* __restrict__ mu_g,
                                               float* __restrict__ dd,
                                               float* __restrict__ g,
                                               float* __restrict__ rhs) {
  int b = blockIdx.x, tid = threadIdx.x;
  __shared__ float nus[MDIM];
  __shared__ float zs[NXP];
  __shared__ float dgs[NXP];
  for (int l = tid; l < NXP; l += CTHR) {
    zs[l]  = (l < NXDIM) ? z[b * NXP + l] : 0.0f;
    dgs[l] = 0.0f;
  }
  for (int l = tid; l < MDIM; l += CTHR) nus[l] = nu[b * MP + l];
  __syncthreads();
  float muv = mu_g[b];
  if (tid < NXDIM) {
    int i = tid;
    float a0 = 0.0f, a1 = 0.0f, a2 = 0.0f, a3 = 0.0f;
    #pragma unroll 1
    for (int m = 0; m < MDIM; m += 4) {      // 324 % 4 == 0
      a0 += A32[(m + 0) * NXP + i] * nus[m + 0];
      a1 += A32[(m + 1) * NXP + i] * nus[m + 1];
      a2 += A32[(m + 2) * NXP + i] * nus[m + 2];
      a3 += A32[(m + 3) * NXP + i] * nus[m + 3];
    }
    float acc = (a0 + a1) + (a2 + a3);
    float zv = zs[i], lv = lam[b * NXP + i], pv = p[b * NXP + i];
    float rz = EPSF * zv + pv - lv + acc;
    float rc = zv * lv - SIGF * muv;
    float ddv = 1.0f / (EPSF + lv / zv);
    float gv = -(rz + rc / zv);
    dd[b * NXP + i] = ddv;
    g[b * NXP + i]  = gv;
    dgs[i] = ddv * gv;
  }
  __syncthreads();
  if (tid < MDIM) {
    float s0 = 0.0f, s1 = 0.0f, s2 = 0.0f, s3 = 0.0f;
    float t0 = 0.0f, t1 = 0.0f, t2 = 0.0f, t3 = 0.0f;
    #pragma unroll 1
    for (int i = 0; i < NXP; i += 4) {       // 736 % 4 == 0; pads are zero
      float w0 = AT32[(size_t)(i + 0) * MP + tid];
      float w1 = AT32[(size_t)(i + 1) * MP + tid];
      float w2 = AT32[(size_t)(i + 2) * MP + tid];
      float w3 = AT32[(size_t)(i + 3) * MP + tid];
      s0 += w0 * zs[i + 0];  t0 += w0 * dgs[i + 0];
      s1 += w1 * zs[i + 1];  t1 += w1 * dgs[i + 1];
      s2 += w2 * zs[i + 2];  t2 += w2 * dgs[i + 2];
      s3 += w3 * zs[i + 3];  t3 += w3 * dgs[i + 3];
    }
    rhs[b * MP + tid] = ((t0 + t1) + (t2 + t3)) + ((s0 + s1) + (s2 + s3)) - bvec[tid];
  }
}

// ADAT[b] upper 64x64 tile pairs, vector f32 FMA. Block = 256 thr, 4x4/thread.
// Grid is (64 batches, 21 tiles) so linear index = b + 64*pr -> XCD = b%8 for
// ALL of batch b's tiles: ADAT stays in the same XCD L2 that k_chol reads.
__global__ __launch_bounds__(256) void k_adat(const float* __restrict__ A32,
                                              const float* __restrict__ dd,
                                              float* __restrict__ ADAT) {
  int b  = blockIdx.x;
  int pr = blockIdx.y;   // 0..20 upper tile pairs of 6x6 tiling
  int ti = 0, prr = pr;
  while (prr >= 6 - ti) { prr -= 6 - ti; ti++; }
  int tj = ti + prr;
  int m0 = ti * 64, n0 = tj * 64;
  __shared__ float Sa[AKC][66];   // [k][row] transposed
  __shared__ float Sb[AKC][66];
  int tid = threadIdx.x;
  int tx = tid & 15, ty = tid >> 4;
  const float* db = dd + b * NXP;
  float acc[4][4];
  #pragma unroll
  for (int r = 0; r < 4; ++r)
    #pragma unroll
    for (int c = 0; c < 4; ++c) acc[r][c] = 0.0f;

  #pragma unroll 1
  for (int ch = 0; ch < ANCH; ++ch) {
    int i0 = ch * AKC;
    __syncthreads();
    #pragma unroll
    for (int q = 0; q < 4; ++q) {
      int row = ty + q * 16;
      int mrow = m0 + row, nrow = n0 + row;
      Sa[tx][row] = (mrow < MDIM) ? A32[(size_t)mrow * NXP + i0 + tx] : 0.0f;
      Sb[tx][row] = (nrow < MDIM) ? A32[(size_t)nrow * NXP + i0 + tx] * db[i0 + tx] : 0.0f;
    }
    __syncthreads();
    #pragma unroll
    for (int k = 0; k < AKC; ++k) {
      float ra[4], rb[4];
      #pragma unroll
      for (int r = 0; r < 4; ++r) ra[r] = Sa[k][ty + 16 * r];
      #pragma unroll
      for (int c = 0; c < 4; ++c) rb[c] = Sb[k][tx + 16 * c];
      #pragma unroll
      for (int r = 0; r < 4; ++r)
        #pragma unroll
        for (int c = 0; c < 4; ++c) acc[r][c] += ra[r] * rb[c];
    }
  }
  float* Mb = ADAT + (size_t)b * LDA * LDA;
  #pragma unroll
  for (int r = 0; r < 4; ++r) {
    int m = m0 + ty + 16 * r;
    if (m >= MDIM) continue;
    #pragma unroll
    for (int c = 0; c < 4; ++c) {
      int n = n0 + tx + 16 * c;
      if (n < MDIM) Mb[(size_t)m * LDA + n] = acc[r][c];
    }
  }
}

// Blocked upper Cholesky (U^T U) + solve, one 1024-thread WG (16 waves) per batch.
// NB=18. Panel prefetched into LDS (coalesced, overlapped with wave-0 diag factor);
// panel solve runs entirely in LDS; cooperative coalesced U write-back.
__global__ __launch_bounds__(1024) void k_chol(float* __restrict__ ADAT,
                                               const float* __restrict__ rhs,
                                               float* __restrict__ dnu) {
  int b = blockIdx.x, tid = threadIdx.x;
  int lane = tid & 63, wid = tid >> 6;      // 16 waves
  float* Mb = ADAT + (size_t)b * LDA * LDA;
  __shared__ float P[NB][PSTR];   // panel rows U[k0+t][j], abs col idx; [324,356) zero
  __shared__ float D[NB][NB + 1]; // diagonal block
  __shared__ float yv[MDIM];      // rhs -> y -> x
  __shared__ float ivp[NB];
  __shared__ float ys[NB];

  for (int l = tid; l < NB * (PSTR - MDIM); l += CTHR) {
    int r = l / (PSTR - MDIM), c = l % (PSTR - MDIM);
    P[r][MDIM + c] = 0.0f;         // zero pad columns once; never written again
  }
  for (int l = tid; l < MDIM; l += CTHR) yv[l] = rhs[b * MP + l];

  #pragma unroll 1
  for (int p = 0; p < NPAN; ++p) {
    int k0 = p * NB, t0 = k0 + NB, rem = MDIM - t0;
    __syncthreads();
    // ---- load diag block cooperatively ----
    if (tid < NB * NB) {
      int r = tid / NB, c = tid % NB;
      D[r][c] = Mb[(size_t)(k0 + r) * LDA + (k0 + c)];
    }
    __syncthreads();
    // ---- wave 0: diag factor (shfl recurrence) ∥ waves 1-15: prefetch panel ----
    if (wid == 0) {
      float dreg[NB];
      #pragma unroll
      for (int r = 0; r < NB; ++r) dreg[r] = (lane < NB) ? D[r][lane] : 0.0f;
      float myiv = 0.0f;
      #pragma unroll
      for (int kk = 0; kk < NB; ++kk) {
        float dk = __shfl(dreg[kk], kk);
        float iv = 1.0f / sqrtf(dk);
        float u  = dreg[kk] * iv;      // row kk scaled: U[kk][lane]
        dreg[kk] = u;
        if (lane == kk) myiv = iv;
        #pragma unroll
        for (int r = kk + 1; r < NB; ++r)
          dreg[r] -= __shfl(u, r) * u; // rank-1: D[r][lane] -= U[kk][r]*U[kk][lane]
      }
      if (lane < NB) {
        ivp[lane] = myiv;
        #pragma unroll
        for (int r = 0; r < NB; ++r) {
          D[r][lane] = dreg[r];
          if (r <= lane) Mb[(size_t)(k0 + r) * LDA + (k0 + lane)] = dreg[r];
        }
      }
    } else {
      int tp = tid - 64;
      for (int l = tp; l < NB * rem; l += CTHR - 64) {
        int r = l / rem, j = l % rem;
        P[r][t0 + j] = Mb[(size_t)(k0 + r) * LDA + (t0 + j)];
      }
    }
    __syncthreads();
    // ---- panel rows (triangular solves, in-LDS) + fused fwd-subst col ----
    {
      bool isY = (tid == rem);
      bool act = (tid < rem) || isY;
      int j = t0 + tid;
      if (act) {
        float val[NB];
        #pragma unroll
        for (int r = 0; r < NB; ++r) {
          float v = isY ? yv[k0 + r] : P[r][j];
          #pragma unroll
          for (int t = 0; t < NB; ++t)
            if (t < r) v -= D[t][r] * val[t];
          v *= ivp[r];
          val[r] = v;
          if (isY) { ys[r] = v; yv[k0 + r] = v; }
          else     { P[r][j] = v; }
        }
      }
    }
    __syncthreads();
    if (rem <= 0) continue;
    // ---- y tail update ----
    if (tid < rem) {
      int j = t0 + tid;
      float s = yv[j];
      #pragma unroll
      for (int t = 0; t < NB; ++t) s -= P[t][j] * ys[t];
      yv[j] = s;
    }
    // ---- cooperative coalesced U panel write-back (~6 stores/thread) ----
    for (int l = tid; l < NB * rem; l += CTHR) {
      int r = l / rem, j = l % rem;
      Mb[(size_t)(k0 + r) * LDA + (t0 + j)] = P[r][t0 + j];
    }
    // ---- trailing update: 32x32 tile per wave, 4x4 regs per lane ----
    {
      int Ni = (rem + 31) >> 5;
      int cnt = Ni * (Ni + 1) / 2;
      for (int tt = wid; tt < cnt; tt += 16) {
        int a = 0, r2 = tt;
        while (r2 >= Ni - a) { r2 -= Ni - a; ++a; }
        int bb = a + r2;
        int i0 = t0 + 32 * a, j0 = t0 + 32 * bb;
        int ib = i0 + (lane >> 3);   // rows ib + 8r
        int jb = j0 + (lane & 7);    // cols jb + 8c
        bool full = (i0 + 31 < MDIM) && (j0 + 31 < MDIM);
        float cv[4][4];
        if (full) {
          #pragma unroll
          for (int r = 0; r < 4; ++r)
            #pragma unroll
            for (int c = 0; c < 4; ++c)
              cv[r][c] = Mb[(size_t)(ib + 8 * r) * LDA + (jb + 8 * c)];
        } else {
          #pragma unroll
          for (int r = 0; r < 4; ++r)
            #pragma unroll
            for (int c = 0; c < 4; ++c) {
              int i = ib + 8 * r, j = jb + 8 * c;
              cv[r][c] = (i < MDIM && j < MDIM) ? Mb[(size_t)i * LDA + j] : 0.0f;
            }
        }
        #pragma unroll
        for (int t = 0; t < NB; ++t) {
          float pi[4], pj[4];
          #pragma unroll
          for (int r = 0; r < 4; ++r) pi[r] = P[t][ib + 8 * r];
          #pragma unroll
          for (int c = 0; c < 4; ++c) pj[c] = P[t][jb + 8 * c];
          #pragma unroll
          for (int r = 0; r < 4; ++r)
            #pragma unroll
            for (int c = 0; c < 4; ++c) cv[r][c] -= pi[r] * pj[c];
        }
        if (full && bb > a) {        // strictly upper tile: unguarded store
          #pragma unroll
          for (int r = 0; r < 4; ++r)
            #pragma unroll
            for (int c = 0; c < 4; ++c)
              Mb[(size_t)(ib + 8 * r) * LDA + (jb + 8 * c)] = cv[r][c];
        } else {
          #pragma unroll
          for (int r = 0; r < 4; ++r)
            #pragma unroll
            for (int c = 0; c < 4; ++c) {
              int i = ib + 8 * r, j = jb + 8 * c;
              if (i < MDIM && j < MDIM && j >= i) Mb[(size_t)i * LDA + j] = cv[r][c];
            }
        }
      }
    }
  }
  // ---- back substitution: U x = y ----
  #pragma unroll 1
  for (int p = NPAN - 1; p >= 0; --p) {
    int k0 = p * NB, t0 = k0 + NB;
    __syncthreads();
    if (tid < NB * NB) {
      int r = tid / NB, c = tid % NB;
      D[r][c] = Mb[(size_t)(k0 + r) * LDA + (k0 + c)];
    }
    __syncthreads();
    if (t0 < MDIM) {  // y[k0+r] -= sum_{j>=t0} U[k0+r][j] * x[j]
      for (int r = wid; r < NB; r += 16) {
        float s = 0.0f;
        for (int j = t0 + lane; j < MDIM; j += 64)
          s += Mb[(size_t)(k0 + r) * LDA + j] * yv[j];
        for (int off = 32; off > 0; off >>= 1) s += __shfl_xor(s, off);
        if (lane == 0) yv[k0 + r] -= s;
      }
    }
    __syncthreads();
    if (tid < 64) {   // wave-0 shfl-based diagonal back-solve
      float accv = 0.0f;
      for (int kk = NB - 1; kk >= 0; --kk) {
        float ad = __shfl(accv, kk);
        float xkk = (yv[k0 + kk] - ad) / D[kk][kk];
        if (lane < kk) accv += D[lane][kk] * xkk;
        if (lane == kk) yv[k0 + kk] = xkk;
      }
    }
  }
  __syncthreads();
  for (int l = tid; l < MDIM; l += CTHR) dnu[b * MP + l] = yv[l];
}

// Fused post(t) + pre(t+1). Incremental atnu = A^T nu maintained exactly:
// atnu' = atnu + alpha * (A^T dnu), reusing the post-phase matvec acc.
__global__ __launch_bounds__(1024) void k_popre(const float* __restrict__ A32,
                                                const float* __restrict__ AT32,
                                                const float* __restrict__ dnu,
                                                const float* __restrict__ p,
                                                const float* __restrict__ bvec,
                                                float* __restrict__ mu_g,
                                                float* __restrict__ dd,
                                                float* __restrict__ g,
                                                float* __restrict__ atnu,
                                                float* __restrict__ z,
                                                float* __restrict__ lam,
                                                float* __restrict__ nu,
                                                float* __restrict__ rhs) {
  int b = blockIdx.x, tid = threadIdx.x;
  int lane = tid & 63, wid = tid >> 6;
  __shared__ float ds[MDIM];
  __shared__ float zs[NXP];
  __shared__ float dgs[NXP];
  __shared__ float wred[16];
  __shared__ float salpha, smu;
  for (int l = tid; l < MDIM; l += CTHR) ds[l] = dnu[b * MP + l];
  for (int l = tid; l < NXP; l += CTHR) {
    if (l >= NXDIM) { zs[l] = 0.0f; dgs[l] = 0.0f; }
  }
  __syncthreads();
  bool act = (tid < NXDIM);
  float inf = __builtin_inff();
  float muv = mu_g[b];
  float zv = 0.0f, lv = 0.0f, dzv = 0.0f, dlv = 0.0f, accv = 0.0f;
  float rm = inf;
  // ---- post phase: step directions + alpha candidates ----
  if (act) {
    int i = tid;
    float a0 = 0.0f, a1 = 0.0f, a2 = 0.0f, a3 = 0.0f;
    #pragma unroll 1
    for (int m = 0; m < MDIM; m += 4) {
      a0 += A32[(m + 0) * NXP + i] * ds[m + 0];
      a1 += A32[(m + 1) * NXP + i] * ds[m + 1];
      a2 += A32[(m + 2) * NXP + i] * ds[m + 2];
      a3 += A32[(m + 3) * NXP + i] * ds[m + 3];
    }
    accv = (a0 + a1) + (a2 + a3);
    zv = z[b * NXP + i]; lv = lam[b * NXP + i];
    float ddv = dd[b * NXP + i], gv = g[b * NXP + i];
    dzv = ddv * (gv - accv);
    float rc = zv * lv - SIGF * muv;
    dlv = -(rc + lv * dzv) / zv;
    float r1 = (dzv < 0.0f) ? (-zv / dzv) : inf;
    float r2 = (dlv < 0.0f) ? (-lv / dlv) : inf;
    rm = fminf(r1, r2);
  }
  for (int off = 32; off > 0; off >>= 1) rm = fminf(rm, __shfl_xor(rm, off));
  if (lane == 0) wred[wid] = rm;
  __syncthreads();
  if (tid == 0) {
    float a = wred[0];
    #pragma unroll
    for (int w = 1; w < 16; ++w) a = fminf(a, wred[w]);
    salpha = fminf(1.0f, 0.99f * a);
  }
  __syncthreads();
  float a = salpha;
  float zn = zv + a * dzv, ln = lv + a * dlv;
  float na = 0.0f;
  if (act) {
    z[b * NXP + tid]   = zn;
    lam[b * NXP + tid] = ln;
    zs[tid] = zn;
    na = atnu[b * NXP + tid] + a * accv;   // A^T nu incremental (exact algebra)
    atnu[b * NXP + tid] = na;
  }
  if (tid < MDIM) nu[b * MP + tid] += a * ds[tid];
  // ---- mu_{t+1} = mean(z_new * lam_new) ----
  float s = act ? zn * ln : 0.0f;
  for (int off = 32; off > 0; off >>= 1) s += __shfl_xor(s, off);
  if (lane == 0) wred[wid] = s;            // safe: alpha reads of wred were pre-barrier
  __syncthreads();
  if (tid == 0) {
    float t = 0.0f;
    #pragma unroll
    for (int w = 0; w < 16; ++w) t += wred[w];
    smu = t / (float)NXDIM;
    mu_g[b] = smu;
  }
  __syncthreads();
  float mun = smu;
  // ---- pre phase (iteration t+1): rz, rc, d, g ----
  if (act) {
    int i = tid;
    float rz = EPSF * zn + p[b * NXP + i] - ln + na;
    float rcn = zn * ln - SIGF * mun;
    float ddn = 1.0f / (EPSF + ln / zn);
    float gn = -(rz + rcn / zn);
    dd[b * NXP + i] = ddn;
    g[b * NXP + i]  = gn;
    dgs[i] = ddn * gn;
  }
  __syncthreads();
  // ---- rhs for next solve ----
  if (tid < MDIM) {
    float s0 = 0.0f, s1 = 0.0f, s2 = 0.0f, s3 = 0.0f;
    float t0 = 0.0f, t1 = 0.0f, t2 = 0.0f, t3 = 0.0f;
    #pragma unroll 1
    for (int i = 0; i < NXP; i += 4) {
      float w0 = AT32[(size_t)(i + 0) * MP + tid];
      float w1 = AT32[(size_t)(i + 1) * MP + tid];
      float w2 = AT32[(size_t)(i + 2) * MP + tid];
      float w3 = AT32[(size_t)(i + 3) * MP + tid];
      s0 += w0 * zs[i + 0];  t0 += w0 * dgs[i + 0];
      s1 += w1 * zs[i + 1];  t1 += w1 * dgs[i + 1];
      s2 += w2 * zs[i + 2];  t2 += w2 * dgs[i + 2];
      s3 += w3 * zs[i + 3];  t3 += w3 * dgs[i + 3];
    }
    rhs[b * MP + tid] = ((t0 + t1) + (t2 + t3)) + ((s0 + s1) + (s2 + s3)) - bvec[tid];
  }
}

__global__ void k_out(const float* __restrict__ z, float* __restrict__ out) {
  int idx = blockIdx.x * 256 + threadIdx.x;
  if (idx >= BSZ * NXDIM) return;
  int b = idx / NXDIM, i = idx % NXDIM;
  out[idx] = z[b * NXP + i];
}

// ---------------- host launcher ----------------

extern "C" void kernel_launch(void* const* d_in, const int* in_sizes, int n_in,
                              void* d_out, int out_size, void* d_ws, size_t ws_size,
                              hipStream_t stream) {
  const float* puz = (const float*)d_in[0];
  const float* Af  = (const float*)d_in[1];
  const float* lz  = (const float*)d_in[2];
  float* out = (float*)d_out;

  char* base = (char*)d_ws;
  size_t off = 0;
  auto alloc = [&](size_t bytes) -> void* {
    void* ptr = base + off;
    off = (off + bytes + 255) & ~(size_t)255;
    return ptr;
  };
  float* A32  = (float*)alloc((size_t)MDIM * NXP * 4);
  float* AT32 = (float*)alloc((size_t)NXP * MP * 4);
  float* p_   = (float*)alloc((size_t)BSZ * NXP * 4);
  float* z_   = (float*)alloc((size_t)BSZ * NXP * 4);
  float* lam_ = (float*)alloc((size_t)BSZ * NXP * 4);
  float* dd_  = (float*)alloc((size_t)BSZ * NXP * 4);
  float* g_   = (float*)alloc((size_t)BSZ * NXP * 4);
  float* atnu_= (float*)alloc((size_t)BSZ * NXP * 4);
  float* nu_  = (float*)alloc((size_t)BSZ * MP * 4);
  float* dnu_ = (float*)alloc((size_t)BSZ * MP * 4);
  float* rhs_ = (float*)alloc((size_t)BSZ * MP * 4);
  float* bvec = (float*)alloc((size_t)MP * 4);
  float* mu_  = (float*)alloc((size_t)BSZ * 4);
  float* ADAT = (float*)alloc((size_t)BSZ * LDA * LDA * 4);
  (void)ws_size; (void)in_sizes; (void)n_in; (void)out_size;

  k_setupA<<<943, 256, 0, stream>>>(Af, A32, AT32);
  k_setupState<<<184, 256, 0, stream>>>(puz, p_, z_, lam_, dd_, nu_, mu_, atnu_);
  k_setupB<<<324, 256, 0, stream>>>(A32, lz, bvec);

  dim3 g4(64, 21);   // batch-major: all of batch b's tiles -> XCD b%8 (matches k_chol)
  k_pre0<<<64, CTHR, 0, stream>>>(A32, AT32, z_, lam_, nu_, p_, bvec, mu_, dd_, g_, rhs_);
  for (int it = 0; it < NIT; ++it) {
    k_adat<<<g4, 256, 0, stream>>>(A32, dd_, ADAT);
    k_chol<<<64, CTHR, 0, stream>>>(ADAT, rhs_, dnu_);
    k_popre<<<64, CTHR, 0, stream>>>(A32, AT32, dnu_, p_, bvec, mu_, dd_, g_,
                                     atnu_, z_, lam_, nu_, rhs_);
  }
  k_out<<<183, 256, 0, stream>>>(z_, out);
}

// Round 12
// 13445.888 us; speedup vs baseline: 1.5711x; 1.1608x over previous
//
#include <hip/hip_runtime.h>
#include <math.h>

// ---------------- problem constants ----------------
#define BSZ   64
#define NXDIM 729
#define NXP   736          // padded (multiple of 16), pad cols are zero
#define MDIM  324
#define MP    328          // padded vector length for m-dim arrays
#define LDA   328          // ADAT leading dim (floats)
#define EPSF  0.1f
#define SIGF  0.1f
#define NIT   30

// Cholesky blocking (NB=18 measured optimum: r8=292us, r9 NB=36=428us)
#define NB    18
#define NPAN  18           // 324 / 18
#define CTHR  1024
#define PSTR  356          // P panel stride: 324 + 32 zero pad (tile reads overshoot <= +30)

// ADAT tiling: 64x64 tiles over 6x6 upper -> 21 pairs, vector f32 FMA
#define AKC   16
#define ANCH  46           // 736 / 16

typedef unsigned long long ull;

// ---------------- setup kernels ----------------

__global__ void k_setupA(const float* __restrict__ Af,
                         float* __restrict__ A32, float* __restrict__ AT32) {
  int idx = blockIdx.x * 256 + threadIdx.x;
  if (idx < MDIM * NXP) {
    int r = idx / NXP, c = idx % NXP;
    A32[idx] = (c < NXDIM) ? Af[r * NXDIM + c] : 0.0f;
  }
  if (idx < NXP * MP) {
    int i = idx / MP, m = idx % MP;
    AT32[idx] = (i < NXDIM && m < MDIM) ? Af[m * NXDIM + i] : 0.0f;
  }
}

__global__ void k_setupState(const float* __restrict__ puz,
                             float* __restrict__ p, float* __restrict__ z,
                             float* __restrict__ lam, float* __restrict__ dd,
                             float* __restrict__ nu, float* __restrict__ mu_g,
                             float* __restrict__ atnu) {
  int idx = blockIdx.x * 256 + threadIdx.x;
  if (idx >= BSZ * NXP) return;
  int b = idx / NXP, i = idx % NXP;
  p[idx]    = (i < NXDIM) ? -puz[b * NXDIM + i] : 0.0f;
  z[idx]    = 1.0f;
  lam[idx]  = 1.0f;
  dd[idx]   = 0.0f;            // pads (i>=729) must stay 0 for k_adat
  atnu[idx] = 0.0f;            // A^T nu0 = 0 (nu0 = 0)
  if (i < MP) nu[b * MP + i] = 0.0f;
  if (i == 0) mu_g[b] = 1.0f;  // mean(z0*lam0) = 1
}

__global__ void k_setupB(const float* __restrict__ A32,
                         const float* __restrict__ lz, float* __restrict__ bvec) {
  int m = blockIdx.x, tid = threadIdx.x;
  __shared__ float red[256];
  float s = 0.0f;
  for (int i = tid; i < NXDIM; i += 256)
    s += A32[m * NXP + i] * expf(lz[i]);
  red[tid] = s; __syncthreads();
  for (int w = 128; w > 0; w >>= 1) { if (tid < w) red[tid] += red[tid + w]; __syncthreads(); }
  if (tid == 0) bvec[m] = red[0];
}

// ---------------- per-iteration kernels ----------------

// Initial pre (runs once): stage1 (rz,rc,d,g) + rhs from initial state.
__global__ __launch_bounds__(1024) void k_pre0(const float* __restrict__ A32,
                                               const float* __restrict__ AT32,
                                               const float* __restrict__ z,
                                               const float* __restrict__ lam,
                                               const float* __restrict__ nu,
                                               const float* __restrict__ p,
                                               const float* __restrict__ bvec,
                                               const float* __restrict__ mu_g,
                                               float* __restrict__ dd,
                                               float* __restrict__ g,
                                               float* __restrict__ rhs) {
  int b = blockIdx.x, tid = threadIdx.x;
  __shared__ float nus[MDIM];
  __shared__ float zs[NXP];
  __shared__ float dgs[NXP];
  for (int l = tid; l < NXP; l += CTHR) {
    zs[l]  = (l < NXDIM) ? z[b * NXP + l] : 0.0f;
    dgs[l] = 0.0f;
  }
  for (int l = tid; l < MDIM; l += CTHR) nus[l] = nu[b * MP + l];
  __syncthreads();
  float muv = mu_g[b];
  if (tid < NXDIM) {
    int i = tid;
    float a0 = 0.0f, a1 = 0.0f, a2 = 0.0f, a3 = 0.0f;
    #pragma unroll 1
    for (int m = 0; m < MDIM; m += 4) {      // 324 % 4 == 0
      a0 += A32[(m + 0) * NXP + i] * nus[m + 0];
      a1 += A32[(m + 1) * NXP + i] * nus[m + 1];
      a2 += A32[(m + 2) * NXP + i] * nus[m + 2];
      a3 += A32[(m + 3) * NXP + i] * nus[m + 3];
    }
    float acc = (a0 + a1) + (a2 + a3);
    float zv = zs[i], lv = lam[b * NXP + i], pv = p[b * NXP + i];
    float rz = EPSF * zv + pv - lv + acc;
    float rc = zv * lv - SIGF * muv;
    float ddv = 1.0f / (EPSF + lv / zv);
    float gv = -(rz + rc / zv);
    dd[b * NXP + i] = ddv;
    g[b * NXP + i]  = gv;
    dgs[i] = ddv * gv;
  }
  __syncthreads();
  if (tid < MDIM) {
    float s0 = 0.0f, s1 = 0.0f, s2 = 0.0f, s3 = 0.0f;
    float t0 = 0.0f, t1 = 0.0f, t2 = 0.0f, t3 = 0.0f;
    #pragma unroll 1
    for (int i = 0; i < NXP; i += 4) {       // 736 % 4 == 0; pads are zero
      float w0 = AT32[(size_t)(i + 0) * MP + tid];
      float w1 = AT32[(size_t)(i + 1) * MP + tid];
      float w2 = AT32[(size_t)(i + 2) * MP + tid];
      float w3 = AT32[(size_t)(i + 3) * MP + tid];
      s0 += w0 * zs[i + 0];  t0 += w0 * dgs[i + 0];
      s1 += w1 * zs[i + 1];  t1 += w1 * dgs[i + 1];
      s2 += w2 * zs[i + 2];  t2 += w2 * dgs[i + 2];
      s3 += w3 * zs[i + 3];  t3 += w3 * dgs[i + 3];
    }
    rhs[b * MP + tid] = ((t0 + t1) + (t2 + t3)) + ((s0 + s1) + (s2 + s3)) - bvec[tid];
  }
}

// ADAT[b] upper 64x64 tile pairs, vector f32 FMA. Block = 256 thr, 4x4/thread,
// BLOCKED ownership (rows 4ty+r, cols 4tx+c): float4 LDS reads + float4 C stores.
__global__ __launch_bounds__(256) void k_adat(const float* __restrict__ A32,
                                              const float* __restrict__ dd,
                                              float* __restrict__ ADAT) {
  int b  = blockIdx.x;
  int pr = blockIdx.y;   // 0..20 upper tile pairs of 6x6 tiling
  int ti = 0, prr = pr;
  while (prr >= 6 - ti) { prr -= 6 - ti; ti++; }
  int tj = ti + prr;
  int m0 = ti * 64, n0 = tj * 64;
  __shared__ float Sa[AKC][68];   // [k][row] transposed; stride 68 (16B-aligned rows)
  __shared__ float Sb[AKC][68];
  int tid = threadIdx.x;
  int tx = tid & 15, ty = tid >> 4;
  const float* db = dd + b * NXP;
  float acc[4][4];
  #pragma unroll
  for (int r = 0; r < 4; ++r)
    #pragma unroll
    for (int c = 0; c < 4; ++c) acc[r][c] = 0.0f;

  #pragma unroll 1
  for (int ch = 0; ch < ANCH; ++ch) {
    int i0 = ch * AKC;
    __syncthreads();
    #pragma unroll
    for (int q = 0; q < 4; ++q) {
      int row = ty + q * 16;
      int mrow = m0 + row, nrow = n0 + row;
      Sa[tx][row] = (mrow < MDIM) ? A32[(size_t)mrow * NXP + i0 + tx] : 0.0f;
      Sb[tx][row] = (nrow < MDIM) ? A32[(size_t)nrow * NXP + i0 + tx] * db[i0 + tx] : 0.0f;
    }
    __syncthreads();
    #pragma unroll
    for (int k = 0; k < AKC; ++k) {
      float4 ra4 = *(const float4*)&Sa[k][4 * ty];
      float4 rb4 = *(const float4*)&Sb[k][4 * tx];
      float rav[4] = {ra4.x, ra4.y, ra4.z, ra4.w};
      float rbv[4] = {rb4.x, rb4.y, rb4.z, rb4.w};
      #pragma unroll
      for (int r = 0; r < 4; ++r)
        #pragma unroll
        for (int c = 0; c < 4; ++c) acc[r][c] += rav[r] * rbv[c];
    }
  }
  float* Mb = ADAT + (size_t)b * LDA * LDA;
  #pragma unroll
  for (int r = 0; r < 4; ++r) {
    int m = m0 + 4 * ty + r;
    if (m >= MDIM) continue;
    int n = n0 + 4 * tx;
    if (n + 3 < MDIM) {
      float4 v; v.x = acc[r][0]; v.y = acc[r][1]; v.z = acc[r][2]; v.w = acc[r][3];
      *(float4*)&Mb[(size_t)m * LDA + n] = v;     // LDA%4==0, n%4==0 -> 16B aligned
    } else {
      #pragma unroll
      for (int c = 0; c < 4; ++c)
        if (n + c < MDIM) Mb[(size_t)m * LDA + n + c] = acc[r][c];
    }
  }
}

// Blocked upper Cholesky (U^T U) + solve, one 1024-thread WG (16 waves) per batch.
// NB=18. Wave-0 loads diag block direct from global + factors (shfl recurrence)
// CONCURRENTLY with waves 1-15 prefetching the panel into LDS. 3 barriers/panel.
__global__ __launch_bounds__(1024) void k_chol(float* __restrict__ ADAT,
                                               const float* __restrict__ rhs,
                                               float* __restrict__ dnu) {
  int b = blockIdx.x, tid = threadIdx.x;
  int lane = tid & 63, wid = tid >> 6;      // 16 waves
  float* Mb = ADAT + (size_t)b * LDA * LDA;
  __shared__ float P[NB][PSTR];   // panel rows U[k0+t][j], abs col idx; [324,356) zero
  __shared__ float D[NB][NB + 1]; // diagonal block
  __shared__ float yv[MDIM];      // rhs -> y -> x
  __shared__ float ivp[NB];
  __shared__ float ys[NB];

  for (int l = tid; l < NB * (PSTR - MDIM); l += CTHR) {
    int r = l / (PSTR - MDIM), c = l % (PSTR - MDIM);
    P[r][MDIM + c] = 0.0f;         // zero pad columns once; never written again
  }
  for (int l = tid; l < MDIM; l += CTHR) yv[l] = rhs[b * MP + l];

  #pragma unroll 1
  for (int p = 0; p < NPAN; ++p) {
    int k0 = p * NB, t0 = k0 + NB, rem = MDIM - t0;
    __syncthreads();
    // ---- wave 0: load diag direct + factor ∥ waves 1-15: prefetch panel ----
    if (wid == 0) {
      float dreg[NB];
      #pragma unroll
      for (int r = 0; r < NB; ++r)
        dreg[r] = (lane < NB) ? Mb[(size_t)(k0 + r) * LDA + k0 + lane] : 0.0f;
      float myiv = 0.0f;
      #pragma unroll
      for (int kk = 0; kk < NB; ++kk) {
        float dk = __shfl(dreg[kk], kk);
        float iv = 1.0f / sqrtf(dk);
        float u  = dreg[kk] * iv;      // row kk scaled: U[kk][lane]
        dreg[kk] = u;
        if (lane == kk) myiv = iv;
        #pragma unroll
        for (int r = kk + 1; r < NB; ++r)
          dreg[r] -= __shfl(u, r) * u; // rank-1: D[r][lane] -= U[kk][r]*U[kk][lane]
      }
      if (lane < NB) {
        ivp[lane] = myiv;
        #pragma unroll
        for (int r = 0; r < NB; ++r) {
          D[r][lane] = dreg[r];
          if (r <= lane) Mb[(size_t)(k0 + r) * LDA + (k0 + lane)] = dreg[r];
        }
      }
    } else {
      int tp = tid - 64;
      for (int l = tp; l < NB * rem; l += CTHR - 64) {
        int r = l / rem, j = l % rem;
        P[r][t0 + j] = Mb[(size_t)(k0 + r) * LDA + (t0 + j)];
      }
    }
    __syncthreads();
    // ---- panel rows (triangular solves, in-LDS) + fused fwd-subst col ----
    {
      bool isY = (tid == rem);
      bool act = (tid < rem) || isY;
      int j = t0 + tid;
      if (act) {
        float val[NB];
        #pragma unroll
        for (int r = 0; r < NB; ++r) {
          float v = isY ? yv[k0 + r] : P[r][j];
          #pragma unroll
          for (int t = 0; t < NB; ++t)
            if (t < r) v -= D[t][r] * val[t];
          v *= ivp[r];
          val[r] = v;
          if (isY) { ys[r] = v; yv[k0 + r] = v; }
          else     { P[r][j] = v; }
        }
      }
    }
    __syncthreads();
    if (rem <= 0) continue;
    // ---- y tail update ----
    if (tid < rem) {
      int j = t0 + tid;
      float s = yv[j];
      #pragma unroll
      for (int t = 0; t < NB; ++t) s -= P[t][j] * ys[t];
      yv[j] = s;
    }
    // ---- cooperative coalesced U panel write-back (~6 stores/thread) ----
    for (int l = tid; l < NB * rem; l += CTHR) {
      int r = l / rem, j = l % rem;
      Mb[(size_t)(k0 + r) * LDA + (t0 + j)] = P[r][t0 + j];
    }
    // ---- trailing update: 32x32 tile per wave, 4x4 regs per lane ----
    {
      int Ni = (rem + 31) >> 5;
      int cnt = Ni * (Ni + 1) / 2;
      for (int tt = wid; tt < cnt; tt += 16) {
        int a = 0, r2 = tt;
        while (r2 >= Ni - a) { r2 -= Ni - a; ++a; }
        int bb = a + r2;
        int i0 = t0 + 32 * a, j0 = t0 + 32 * bb;
        int ib = i0 + (lane >> 3);   // rows ib + 8r
        int jb = j0 + (lane & 7);    // cols jb + 8c
        bool full = (i0 + 31 < MDIM) && (j0 + 31 < MDIM);
        float cv[4][4];
        if (full) {
          #pragma unroll
          for (int r = 0; r < 4; ++r)
            #pragma unroll
            for (int c = 0; c < 4; ++c)
              cv[r][c] = Mb[(size_t)(ib + 8 * r) * LDA + (jb + 8 * c)];
        } else {
          #pragma unroll
          for (int r = 0; r < 4; ++r)
            #pragma unroll
            for (int c = 0; c < 4; ++c) {
              int i = ib + 8 * r, j = jb + 8 * c;
              cv[r][c] = (i < MDIM && j < MDIM) ? Mb[(size_t)i * LDA + j] : 0.0f;
            }
        }
        #pragma unroll
        for (int t = 0; t < NB; ++t) {
          float pi[4], pj[4];
          #pragma unroll
          for (int r = 0; r < 4; ++r) pi[r] = P[t][ib + 8 * r];
          #pragma unroll
          for (int c = 0; c < 4; ++c) pj[c] = P[t][jb + 8 * c];
          #pragma unroll
          for (int r = 0; r < 4; ++r)
            #pragma unroll
            for (int c = 0; c < 4; ++c) cv[r][c] -= pi[r] * pj[c];
        }
        if (full && bb > a) {        // strictly upper tile: unguarded store
          #pragma unroll
          for (int r = 0; r < 4; ++r)
            #pragma unroll
            for (int c = 0; c < 4; ++c)
              Mb[(size_t)(ib + 8 * r) * LDA + (jb + 8 * c)] = cv[r][c];
        } else {
          #pragma unroll
          for (int r = 0; r < 4; ++r)
            #pragma unroll
            for (int c = 0; c < 4; ++c) {
              int i = ib + 8 * r, j = jb + 8 * c;
              if (i < MDIM && j < MDIM && j >= i) Mb[(size_t)i * LDA + j] = cv[r][c];
            }
        }
      }
    }
  }
  // ---- back substitution: U x = y ----
  #pragma unroll 1
  for (int p = NPAN - 1; p >= 0; --p) {
    int k0 = p * NB, t0 = k0 + NB;
    __syncthreads();
    if (tid < NB * NB) {
      int r = tid / NB, c = tid % NB;
      D[r][c] = Mb[(size_t)(k0 + r) * LDA + (k0 + c)];
    }
    __syncthreads();
    if (t0 < MDIM) {  // y[k0+r] -= sum_{j>=t0} U[k0+r][j] * x[j]
      for (int r = wid; r < NB; r += 16) {
        float s = 0.0f;
        for (int j = t0 + lane; j < MDIM; j += 64)
          s += Mb[(size_t)(k0 + r) * LDA + j] * yv[j];
        for (int off = 32; off > 0; off >>= 1) s += __shfl_xor(s, off);
        if (lane == 0) yv[k0 + r] -= s;
      }
    }
    __syncthreads();
    if (tid < 64) {   // wave-0 shfl-based diagonal back-solve
      float accv = 0.0f;
      for (int kk = NB - 1; kk >= 0; --kk) {
        float ad = __shfl(accv, kk);
        float xkk = (yv[k0 + kk] - ad) / D[kk][kk];
        if (lane < kk) accv += D[lane][kk] * xkk;
        if (lane == kk) yv[k0 + kk] = xkk;
      }
    }
  }
  __syncthreads();
  for (int l = tid; l < MDIM; l += CTHR) dnu[b * MP + l] = yv[l];
}

// Fused post(t) + pre(t+1). Incremental atnu = A^T nu maintained exactly.
// rhs via A*(z + d*g) with wave-parallel coalesced A-row dots (16 waves).
__global__ __launch_bounds__(1024) void k_popre(const float* __restrict__ A32,
                                                const float* __restrict__ dnu,
                                                const float* __restrict__ p,
                                                const float* __restrict__ bvec,
                                                float* __restrict__ mu_g,
                                                float* __restrict__ dd,
                                                float* __restrict__ g,
                                                float* __restrict__ atnu,
                                                float* __restrict__ z,
                                                float* __restrict__ lam,
                                                float* __restrict__ nu,
                                                float* __restrict__ rhs) {
  int b = blockIdx.x, tid = threadIdx.x;
  int lane = tid & 63, wid = tid >> 6;
  __shared__ float ds[MDIM];
  __shared__ float vs[NXP];       // z_new + d_new*g_new (pads zero)
  __shared__ float wred[16];
  __shared__ float salpha, smu;
  for (int l = tid; l < MDIM; l += CTHR) ds[l] = dnu[b * MP + l];
  for (int l = tid; l < NXP; l += CTHR) {
    if (l >= NXDIM) vs[l] = 0.0f;
  }
  __syncthreads();
  bool act = (tid < NXDIM);
  float inf = __builtin_inff();
  float muv = mu_g[b];
  float zv = 0.0f, lv = 0.0f, dzv = 0.0f, dlv = 0.0f, accv = 0.0f;
  float rm = inf;
  // ---- post phase: step directions + alpha candidates ----
  if (act) {
    int i = tid;
    float a0 = 0.0f, a1 = 0.0f, a2 = 0.0f, a3 = 0.0f;
    #pragma unroll 1
    for (int m = 0; m < MDIM; m += 4) {
      a0 += A32[(m + 0) * NXP + i] * ds[m + 0];
      a1 += A32[(m + 1) * NXP + i] * ds[m + 1];
      a2 += A32[(m + 2) * NXP + i] * ds[m + 2];
      a3 += A32[(m + 3) * NXP + i] * ds[m + 3];
    }
    accv = (a0 + a1) + (a2 + a3);
    zv = z[b * NXP + i]; lv = lam[b * NXP + i];
    float ddv = dd[b * NXP + i], gv = g[b * NXP + i];
    dzv = ddv * (gv - accv);
    float rc = zv * lv - SIGF * muv;
    dlv = -(rc + lv * dzv) / zv;
    float r1 = (dzv < 0.0f) ? (-zv / dzv) : inf;
    float r2 = (dlv < 0.0f) ? (-lv / dlv) : inf;
    rm = fminf(r1, r2);
  }
  for (int off = 32; off > 0; off >>= 1) rm = fminf(rm, __shfl_xor(rm, off));
  if (lane == 0) wred[wid] = rm;
  __syncthreads();
  if (tid == 0) {
    float a = wred[0];
    #pragma unroll
    for (int w = 1; w < 16; ++w) a = fminf(a, wred[w]);
    salpha = fminf(1.0f, 0.99f * a);
  }
  __syncthreads();
  float a = salpha;
  float zn = zv + a * dzv, ln = lv + a * dlv;
  float na = 0.0f;
  if (act) {
    z[b * NXP + tid]   = zn;
    lam[b * NXP + tid] = ln;
    na = atnu[b * NXP + tid] + a * accv;   // A^T nu incremental (exact algebra)
    atnu[b * NXP + tid] = na;
  }
  if (tid < MDIM) nu[b * MP + tid] += a * ds[tid];
  // ---- mu_{t+1} = mean(z_new * lam_new) ----
  float s = act ? zn * ln : 0.0f;
  for (int off = 32; off > 0; off >>= 1) s += __shfl_xor(s, off);
  if (lane == 0) wred[wid] = s;            // safe: alpha reads of wred were pre-barrier
  __syncthreads();
  if (tid == 0) {
    float t = 0.0f;
    #pragma unroll
    for (int w = 0; w < 16; ++w) t += wred[w];
    smu = t / (float)NXDIM;
    mu_g[b] = smu;
  }
  __syncthreads();
  float mun = smu;
  // ---- pre phase (iteration t+1): rz, rc, d, g; vs = z + d*g ----
  if (act) {
    int i = tid;
    float rz = EPSF * zn + p[b * NXP + i] - ln + na;
    float rcn = zn * ln - SIGF * mun;
    float ddn = 1.0f / (EPSF + ln / zn);
    float gn = -(rz + rcn / zn);
    dd[b * NXP + i] = ddn;
    g[b * NXP + i]  = gn;
    vs[i] = zn + ddn * gn;
  }
  __syncthreads();
  // ---- rhs = A * vs - b : wave-parallel coalesced A-row dots ----
  for (int m = wid; m < MDIM; m += 16) {
    float sm = 0.0f;
    for (int i = lane; i < NXP; i += 64)
      sm += A32[(size_t)m * NXP + i] * vs[i];
    for (int off = 32; off > 0; off >>= 1) sm += __shfl_xor(sm, off);
    if (lane == 0) rhs[b * MP + m] = sm - bvec[m];
  }
}

__global__ void k_out(const float* __restrict__ z, float* __restrict__ out) {
  int idx = blockIdx.x * 256 + threadIdx.x;
  if (idx >= BSZ * NXDIM) return;
  int b = idx / NXDIM, i = idx % NXDIM;
  out[idx] = z[b * NXP + i];
}

// ---------------- host launcher ----------------

extern "C" void kernel_launch(void* const* d_in, const int* in_sizes, int n_in,
                              void* d_out, int out_size, void* d_ws, size_t ws_size,
                              hipStream_t stream) {
  const float* puz = (const float*)d_in[0];
  const float* Af  = (const float*)d_in[1];
  const float* lz  = (const float*)d_in[2];
  float* out = (float*)d_out;

  char* base = (char*)d_ws;
  size_t off = 0;
  auto alloc = [&](size_t bytes) -> void* {
    void* ptr = base + off;
    off = (off + bytes + 255) & ~(size_t)255;
    return ptr;
  };
  float* A32  = (float*)alloc((size_t)MDIM * NXP * 4);
  float* AT32 = (float*)alloc((size_t)NXP * MP * 4);
  float* p_   = (float*)alloc((size_t)BSZ * NXP * 4);
  float* z_   = (float*)alloc((size_t)BSZ * NXP * 4);
  float* lam_ = (float*)alloc((size_t)BSZ * NXP * 4);
  float* dd_  = (float*)alloc((size_t)BSZ * NXP * 4);
  float* g_   = (float*)alloc((size_t)BSZ * NXP * 4);
  float* atnu_= (float*)alloc((size_t)BSZ * NXP * 4);
  float* nu_  = (float*)alloc((size_t)BSZ * MP * 4);
  float* dnu_ = (float*)alloc((size_t)BSZ * MP * 4);
  float* rhs_ = (float*)alloc((size_t)BSZ * MP * 4);
  float* bvec = (float*)alloc((size_t)MP * 4);
  float* mu_  = (float*)alloc((size_t)BSZ * 4);
  float* ADAT = (float*)alloc((size_t)BSZ * LDA * LDA * 4);
  (void)ws_size; (void)in_sizes; (void)n_in; (void)out_size;

  k_setupA<<<943, 256, 0, stream>>>(Af, A32, AT32);
  k_setupState<<<184, 256, 0, stream>>>(puz, p_, z_, lam_, dd_, nu_, mu_, atnu_);
  k_setupB<<<324, 256, 0, stream>>>(A32, lz, bvec);

  dim3 g4(64, 21);   // batch-major tile grid
  k_pre0<<<64, CTHR, 0, stream>>>(A32, AT32, z_, lam_, nu_, p_, bvec, mu_, dd_, g_, rhs_);
  for (int it = 0; it < NIT; ++it) {
    k_adat<<<g4, 256, 0, stream>>>(A32, dd_, ADAT);
    k_chol<<<64, CTHR, 0, stream>>>(ADAT, rhs_, dnu_);
    k_popre<<<64, CTHR, 0, stream>>>(A32, dnu_, p_, bvec, mu_, dd_, g_,
                                     atnu_, z_, lam_, nu_, rhs_);
  }
  k_out<<<183, 256, 0, stream>>>(z_, out);
}